// Round 12
// baseline (64.137 us; speedup 1.0000x reference)
//
#include <hip/hip_runtime.h>
#include <hip/hip_bf16.h>

// B=8, C1=256, HW=4096 (N=32768), Ch=128, C2=256, E=4, K=2
// 3-kernel pipeline, arithmetic bit-identical to the round-11 PASSING kernel.
// ws layout (u16 units):
//   W1c [c4=4][half hi/lo][128][64] swz3 @0       (65536)
//   WeP [e=4][128][128] swz4         @65536       (65536)
//   W3P [h=2][128][128] swz4         @131072      (32768)
//   XIN [32768 px][128] bf16 swz4    @163840      (4194304)
//   MOE [32768 px][128] bf16 swz4    @4358144     (4194304)
//   RW  f32 [32768][4]               @u16 8552448 (262144 u16)
// total ~17.4 MB of d_ws.

typedef unsigned short u16;
typedef unsigned int   u32;
typedef __attribute__((ext_vector_type(8))) short short8;
typedef __attribute__((ext_vector_type(4))) float f32x4;

#define MFMA16 __builtin_amdgcn_mfma_f32_16x16x32_bf16

#define W1_OFF   0
#define WE_OFF   65536
#define W3_OFF   131072
#define XIN_OFF  163840
#define MOE_OFF  4358144
#define RW_OFFU  8552448

__device__ __forceinline__ float silu_f(float v) { return v / (1.0f + __expf(-v)); }
__device__ __forceinline__ u16 f2bf(float f) {
    u32 u = __float_as_uint(f);
    return (u16)((u + 0x7fff + ((u >> 16) & 1)) >> 16);
}
__device__ __forceinline__ float bf2f(u16 h) { return __uint_as_float(((u32)h) << 16); }
__device__ __forceinline__ u32 pkbf(float a, float b) {
    __hip_bfloat162 h2 = __float22bfloat162_rn(make_float2(a, b));
    u32 r; __builtin_memcpy(&r, &h2, 4); return r;
}
__device__ __forceinline__ int key3(int r) { return (r ^ (r >> 2)) & 7; }
__device__ __forceinline__ int key2(int r) { return (r ^ (r >> 2)) & 3; }

__global__ void prep_weights(const float* __restrict__ W1,
                             const float* __restrict__ We,
                             const float* __restrict__ W3,
                             u16* __restrict__ ws)
{
    int idx = blockIdx.x * 256 + threadIdx.x;
    if (idx < 65536) {                        // W1: K-chunks of 64, hi/lo, swz3
        int c4 = idx >> 14, r = idx & 16383;
        int half = r >> 13, q = r & 8191;
        int o = q >> 6, rem = q & 63;
        int ps = rem >> 3, t = rem & 7;
        int gi = (ps ^ key3(o)) & 7;
        float v = W1[o * 256 + c4 * 64 + gi * 8 + t];
        u16 h = f2bf(v);
        ws[idx] = half ? f2bf(v - bf2f(h)) : h;
    } else if (idx < 131072) {                // We center taps, swz4
        int i = idx - 65536;
        int e = i >> 14, r = i & 16383;
        int o = r >> 7, rem = r & 127;
        int ps = rem >> 3, t = rem & 7;
        int gi = (ps & 8) | ((ps ^ key3(o)) & 7);
        ws[idx] = f2bf(We[(size_t)(((e * 128 + o) * 128 + gi * 8 + t) * 9) + 4]);
    } else if (idx < 163840) {                // W3 halves, swz4
        int i = idx - 131072;
        int h = i >> 14, r = i & 16383;
        int o = r >> 7, rem = r & 127;
        int ps = rem >> 3, t = rem & 7;
        int gi = (ps & 8) | ((ps ^ key3(o)) & 7);
        ws[131072 + i] = f2bf(W3[(size_t)(h * 128 + o) * 128 + gi * 8 + t]);
    }
}

// Linear DMA of ITER*512 16B-units (512-thread blocks).
template<int ITER>
__device__ __forceinline__ void stage512(const u16* __restrict__ g, u16* l, int tid) {
#pragma unroll
    for (int i = 0; i < ITER; ++i)
        __builtin_amdgcn_global_load_lds(g + (size_t)(i * 512 + tid) * 8,
                                         l + (size_t)(i * 512 + (tid & 448)) * 8, 16, 0, 0);
}

// ============ Kernel A: GEMM1 (split-bf16 4-pass) + router ============
// 256 blocks x 512 thr; 128 px/block; 96 KB LDS; one barrier per K-chunk of 32.
__global__ __launch_bounds__(512, 1)
void k_gemm1(const float* __restrict__ x, const float* __restrict__ b1g,
             const float* __restrict__ Wrg, const float* __restrict__ brg,
             const u16* __restrict__ wbf, u16* __restrict__ xinG,
             float* __restrict__ rwG)
{
    __shared__ __align__(16) u16 sm[49152];   // 96 KB
    u16* const wb0  = sm;                      // chunk buf: hi[128][64] | lo[128][64]
    u16* const wb1  = sm + 16384;
    u16* const ahi0 = sm + 32768;              // [128][32]
    u16* const alo0 = sm + 36864;
    u16* const ahi1 = sm + 40960;
    u16* const alo1 = sm + 45056;

    const int tid = threadIdx.x;
    const int l = tid & 63, w = tid >> 6;      // w 0..7
    const int lr = l & 15, g = l >> 4;
    const int mrow = 16 * w + 4 * g;
    const int arow = 16 * w + lr;
    const int ak2 = key2(lr);
    int ok3[8];
#pragma unroll
    for (int f = 0; f < 8; ++f) ok3[f] = key3(16 * f + lr);

    const int n0 = blockIdx.x << 7;            // 128 px, within one image
    const float* xb = x + ((size_t)(n0 >> 12) * 256) * 4096 + (n0 & 4095);

    stage512<4>(wbf + W1_OFF, wb0, tid);       // W1 chunk 0

    const int c2 = tid >> 5;                   // ch-pair 0..15
    const int m4 = (tid & 31) << 2;            // px row base
    float4 fa = *(const float4*)&xb[(size_t)(2 * c2) * 4096 + m4];
    float4 fb = *(const float4*)&xb[(size_t)(2 * c2 + 1) * 4096 + m4];

    f32x4 acc1[8];
#pragma unroll
    for (int f = 0; f < 8; ++f) acc1[f] = (f32x4){0.f, 0.f, 0.f, 0.f};

#pragma unroll 1
    for (int kc = 0; kc < 8; ++kc) {
        {   // split conversion -> A[kc&1], 2-bit swizzled [128][32]
            u32* H = (u32*)((kc & 1) ? ahi1 : ahi0);
            u32* L = (u32*)((kc & 1) ? alo1 : alo0);
            float fav[4] = {fa.x, fa.y, fa.z, fa.w};
            float fbv[4] = {fb.x, fb.y, fb.z, fb.w};
#pragma unroll
            for (int r = 0; r < 4; ++r) {
                int row = m4 + r;
                u32 hi = pkbf(fav[r], fbv[r]);
                float la = fav[r] - __uint_as_float(hi << 16);
                float lb = fbv[r] - __uint_as_float(hi & 0xffff0000u);
                int ui = row * 16 + ((((c2 >> 2) ^ key2(row)) & 3) << 2) + (c2 & 3);
                H[ui] = hi; L[ui] = pkbf(la, lb);
            }
        }
        __syncthreads();   // drains: A writes + W1 chunk (kc>>1) DMA (issued a full phase ago)
        if (kc == 0 || kc == 2 || kc == 4) {
            int c = kc / 2 + 1;
            stage512<4>(wbf + W1_OFF + c * 16384, (c & 1) ? wb1 : wb0, tid);
        }
        if (kc < 7) {      // x prefetch for kc+1: flies under MFMA
            fa = *(const float4*)&xb[(size_t)((kc + 1) * 32 + 2 * c2) * 4096 + m4];
            fb = *(const float4*)&xb[(size_t)((kc + 1) * 32 + 2 * c2 + 1) * 4096 + m4];
        }
        {
            const u16* WB = ((kc >> 1) & 1) ? wb1 : wb0;
            const u16* AH = (kc & 1) ? ahi1 : ahi0;
            const u16* AL = (kc & 1) ? alo1 : alo0;
            int aoff = arow * 32 + ((g ^ ak2) << 3);
            short8 ah = *(const short8*)&AH[aoff];
            short8 al = *(const short8*)&AL[aoff];
            int gi = (kc & 1) * 4 + g;
#pragma unroll
            for (int f = 0; f < 8; ++f) {
                int bo = (16 * f + lr) * 64 + (((gi ^ ok3[f]) & 7) << 3);
                short8 bh = *(const short8*)&WB[bo];
                short8 bl = *(const short8*)&WB[8192 + bo];
                acc1[f] = MFMA16(ah, bh, acc1[f], 0, 0, 0);
                acc1[f] = MFMA16(al, bh, acc1[f], 0, 0, 0);
                acc1[f] = MFMA16(ah, bl, acc1[f], 0, 0, 0);
                acc1[f] = MFMA16(al, bl, acc1[f], 0, 0, 0);
            }
        }
    }

    // ===== epilogue: xin fp32, swizzled bf16 -> XIN, fp32 router -> RW =====
    float xin[8][4];
#pragma unroll
    for (int f = 0; f < 8; ++f) {
        float bias = b1g[16 * f + lr];
#pragma unroll
        for (int i = 0; i < 4; ++i) xin[f][i] = silu_f(acc1[f][i] + bias);
    }
#pragma unroll
    for (int f = 0; f < 8; ++f) {
        int c = 16 * f + lr, cg = c >> 3;
#pragma unroll
        for (int i = 0; i < 4; ++i) {
            int m = mrow + i;
            int ps = (cg & 8) | ((cg ^ key3(m)) & 7);
            xinG[(size_t)(n0 + m) * 128 + ps * 8 + (c & 7)] = f2bf(xin[f][i]);
        }
    }
    float lg[4][4];
#pragma unroll
    for (int e = 0; e < 4; ++e)
#pragma unroll
        for (int i = 0; i < 4; ++i) lg[e][i] = 0.f;
#pragma unroll
    for (int f = 0; f < 8; ++f) {
        int c = 16 * f + lr;
        float w0 = Wrg[c], w1 = Wrg[128 + c], w2 = Wrg[256 + c], w3 = Wrg[384 + c];
#pragma unroll
        for (int i = 0; i < 4; ++i) {
            float xv = xin[f][i];
            lg[0][i] += xv * w0; lg[1][i] += xv * w1;
            lg[2][i] += xv * w2; lg[3][i] += xv * w3;
        }
    }
#pragma unroll
    for (int d = 1; d < 16; d <<= 1)
#pragma unroll
        for (int e = 0; e < 4; ++e)
#pragma unroll
            for (int i = 0; i < 4; ++i)
                lg[e][i] += __shfl_xor(lg[e][i], d, 64);

    float br0 = brg[0], br1 = brg[1], br2 = brg[2], br3 = brg[3];
    if (lr == 0) {
#pragma unroll
        for (int i = 0; i < 4; ++i) {
            float le0 = lg[0][i] + br0, le1 = lg[1][i] + br1;
            float le2 = lg[2][i] + br2, le3 = lg[3][i] + br3;
            int c0 = (le1 > le0) + (le2 > le0) + (le3 > le0);
            int c1 = (le0 >= le1) + (le2 > le1) + (le3 > le1);
            int c2r = (le0 >= le2) + (le1 >= le2) + (le3 > le2);
            int c3 = (le0 >= le3) + (le1 >= le3) + (le2 >= le3);
            float m = fmaxf(fmaxf(le0, le1), fmaxf(le2, le3));
            float p0 = (c0 < 2) ? __expf(le0 - m) : 0.f;
            float p1 = (c1 < 2) ? __expf(le1 - m) : 0.f;
            float p2 = (c2r < 2) ? __expf(le2 - m) : 0.f;
            float p3 = (c3 < 2) ? __expf(le3 - m) : 0.f;
            float inv = 1.0f / (p0 + p1 + p2 + p3);
            float4 v; v.x = p0 * inv; v.y = p1 * inv; v.z = p2 * inv; v.w = p3 * inv;
            *(float4*)&rwG[(size_t)(n0 + mrow + i) * 4] = v;
        }
    }
}

// ============ Kernel B: experts (dense 4x, weighted accumulate) ============
// 256 blocks x 512 thr; 96 KB LDS; expert chunks 2-deep chained; 5 barriers.
__global__ __launch_bounds__(512, 1)
void k_experts(const float* __restrict__ beg, const u16* __restrict__ wbf,
               const u16* __restrict__ xinG, const float* __restrict__ rwG,
               u16* __restrict__ moeG)
{
    __shared__ __align__(16) u16 sm[49152];
    u16* const eb0 = sm;             // [128][128]
    u16* const eb1 = sm + 16384;
    u16* const xt  = sm + 32768;     // xin tile [128][128]

    const int tid = threadIdx.x;
    const int l = tid & 63, w = tid >> 6;
    const int lr = l & 15, g = l >> 4;
    const int mrow = 16 * w + 4 * g;
    const int arow = 16 * w + lr;
    const int ak3 = key3(arow);
    int ok3[8];
#pragma unroll
    for (int f = 0; f < 8; ++f) ok3[f] = key3(16 * f + lr);

    const int n0 = blockIdx.x << 7;

    stage512<4>(wbf + WE_OFF, eb0, tid);
    stage512<4>(wbf + WE_OFF + 16384, eb1, tid);
    stage512<4>(xinG + (size_t)n0 * 128, xt, tid);

    float rwa[4][4];
#pragma unroll
    for (int i = 0; i < 4; ++i) {
        float4 v = *(const float4*)&rwG[(size_t)(n0 + mrow + i) * 4];
        rwa[0][i] = v.x; rwa[1][i] = v.y; rwa[2][i] = v.z; rwa[3][i] = v.w;
    }
    float bev[4][8];
#pragma unroll
    for (int e = 0; e < 4; ++e)
#pragma unroll
        for (int f = 0; f < 8; ++f) bev[e][f] = beg[e * 128 + 16 * f + lr];

    f32x4 macc[8];
#pragma unroll
    for (int f = 0; f < 8; ++f) macc[f] = (f32x4){0.f, 0.f, 0.f, 0.f};

    __syncthreads();                 // drains e0, e1, xin tile

#pragma unroll 1
    for (int e = 0; e < 4; ++e) {
        const u16* Wb = (e & 1) ? eb1 : eb0;
        f32x4 acce[8];
#pragma unroll
        for (int f = 0; f < 8; ++f) acce[f] = (f32x4){0.f, 0.f, 0.f, 0.f};
#pragma unroll
        for (int ks = 0; ks < 4; ++ks) {
            int gi = ks * 4 + g;
            int psA = (gi & 8) | ((gi ^ ak3) & 7);
            short8 a = *(const short8*)&xt[arow * 128 + psA * 8];
#pragma unroll
            for (int f = 0; f < 8; ++f) {
                int psB = (gi & 8) | ((gi ^ ok3[f]) & 7);
                short8 bb = *(const short8*)&Wb[(16 * f + lr) * 128 + psB * 8];
                acce[f] = MFMA16(a, bb, acce[f], 0, 0, 0);
            }
        }
#pragma unroll
        for (int f = 0; f < 8; ++f)
#pragma unroll
            for (int i = 0; i < 4; ++i)
                macc[f][i] += rwa[e][i] * silu_f(acce[f][i] + bev[e][f]);
        __syncthreads();             // Wb readers done; drains chunk e+1
        if (e < 2) stage512<4>(wbf + WE_OFF + (e + 2) * 16384, (e & 1) ? eb1 : eb0, tid);
    }
    // store moe swizzled bf16
#pragma unroll
    for (int f = 0; f < 8; ++f) {
        int c = 16 * f + lr, cg = c >> 3;
#pragma unroll
        for (int i = 0; i < 4; ++i) {
            int m = mrow + i;
            int ps = (cg & 8) | ((cg ^ key3(m)) & 7);
            moeG[(size_t)(n0 + m) * 128 + ps * 8 + (c & 7)] = f2bf(macc[f][i]);
        }
    }
}

// ============ Kernel C: GEMM3 + residual ============
// 256 blocks x 512 thr; 128 KB LDS; W3 halves sequential; 6 barriers.
__global__ __launch_bounds__(512, 1)
void k_gemm3(const float* __restrict__ x, const float* __restrict__ b3g,
             const u16* __restrict__ wbf, const u16* __restrict__ moeG,
             float* __restrict__ out)
{
    __shared__ __align__(16) u16 sm[65536];   // 128 KB
    u16*   const w3s = sm;                    // [128][128] (one half)
    u16*   const mt  = sm + 16384;            // moe tile [128][128]
    float* const sY  = (float*)(sm + 32768);  // [128 ch][128 px] f32 swz

    const int tid = threadIdx.x;
    const int l = tid & 63, w = tid >> 6;
    const int lr = l & 15, g = l >> 4;
    const int mrow = 16 * w + 4 * g;
    const int arow = 16 * w + lr;
    const int ak3 = key3(arow);
    int ok3[8];
#pragma unroll
    for (int f = 0; f < 8; ++f) ok3[f] = key3(16 * f + lr);

    const int n0 = blockIdx.x << 7;
    const float* xb = x   + ((size_t)(n0 >> 12) * 256) * 4096 + (n0 & 4095);
    float*       ob = out + ((size_t)(n0 >> 12) * 256) * 4096 + (n0 & 4095);

    stage512<4>(wbf + W3_OFF, w3s, tid);
    stage512<4>(moeG + (size_t)n0 * 128, mt, tid);
    __syncthreads();

#pragma unroll 1
    for (int h = 0; h < 2; ++h) {
        f32x4 acc3[8];
#pragma unroll
        for (int f = 0; f < 8; ++f) acc3[f] = (f32x4){0.f, 0.f, 0.f, 0.f};
#pragma unroll
        for (int ks = 0; ks < 4; ++ks) {
            int gi = ks * 4 + g;
            int psA = (gi & 8) | ((gi ^ ak3) & 7);
            short8 a = *(const short8*)&mt[arow * 128 + psA * 8];
#pragma unroll
            for (int f = 0; f < 8; ++f) {
                int psB = (gi & 8) | ((gi ^ ok3[f]) & 7);
                short8 bb = *(const short8*)&w3s[(16 * f + lr) * 128 + psB * 8];
                acc3[f] = MFMA16(a, bb, acc3[f], 0, 0, 0);
            }
        }
        __syncthreads();             // w3s(h) readers done; (h=0:) sY free
        if (h == 0) stage512<4>(wbf + W3_OFF + 16384, w3s, tid);  // W3 h1
        int mg = mrow >> 2;          // 4w+g, 0..31
#pragma unroll
        for (int f = 0; f < 8; ++f) {
            int c = 16 * f + lr;
            float bias = b3g[h * 128 + c];
            float4 v;
            v.x = silu_f(acc3[f][0] + bias);
            v.y = silu_f(acc3[f][1] + bias);
            v.z = silu_f(acc3[f][2] + bias);
            v.w = silu_f(acc3[f][3] + bias);
            int ps = (mg & 24) | ((mg ^ key3(c)) & 7);
            *(float4*)&sY[c * 128 + ps * 4] = v;
        }
        __syncthreads();             // sY visible; drains W3 h1
#pragma unroll
        for (int q = 0; q < 8; ++q) {
            int idx = q * 512 + tid;
            int c = idx >> 5, mq = idx & 31;
            int ps = (mq & 24) | ((mq ^ key3(c)) & 7);
            float4 vy = *(const float4*)&sY[c * 128 + ps * 4];
            size_t goff = (size_t)(h * 128 + c) * 4096 + (mq << 2);
            float4 r = *(const float4*)&xb[goff];
            vy.x += r.x; vy.y += r.y; vy.z += r.z; vy.w += r.w;
            *(float4*)&ob[goff] = vy;
        }
        if (h == 0) __syncthreads(); // sY readers done before h=1 overwrites
    }
}

extern "C" void kernel_launch(void* const* d_in, const int* in_sizes, int n_in,
                              void* d_out, int out_size, void* d_ws, size_t ws_size,
                              hipStream_t stream)
{
    const float* x  = (const float*)d_in[0];
    const float* W1 = (const float*)d_in[1];
    const float* b1 = (const float*)d_in[2];
    const float* Wr = (const float*)d_in[3];
    const float* br = (const float*)d_in[4];
    const float* We = (const float*)d_in[5];
    const float* be = (const float*)d_in[6];
    const float* W3 = (const float*)d_in[7];
    const float* b3 = (const float*)d_in[8];
    float* outp = (float*)d_out;

    u16*   wbf  = (u16*)d_ws;
    u16*   xinG = wbf + XIN_OFF;
    u16*   moeG = wbf + MOE_OFF;
    float* rwG  = (float*)(wbf + RW_OFFU);

    hipLaunchKernelGGL(prep_weights, dim3(640), dim3(256), 0, stream,
                       W1, We, W3, wbf);
    hipLaunchKernelGGL(k_gemm1, dim3(256), dim3(512), 0, stream,
                       x, b1, Wr, br, wbf, xinG, rwG);
    hipLaunchKernelGGL(k_experts, dim3(256), dim3(512), 0, stream,
                       be, wbf, xinG, rwG, moeG);
    hipLaunchKernelGGL(k_gemm3, dim3(256), dim3(512), 0, stream,
                       x, b3, wbf, moeG, outp);
}

// Round 13
// 51.109 us; speedup vs baseline: 1.2549x; 1.2549x over previous
//
#include <hip/hip_runtime.h>
#include <hip/hip_bf16.h>

// B=8, C1=256, HW=4096 (N=32768), Ch=128, C2=256, E=4, K=2
// ws layout (u16) — identical to R11:
//   W1hi [kc=4][128][72] @0        (36864)
//   W1lo [kc=4][128][72] @36864    (36864)
//   Wec  [e=4][128][128] swz @73728  (65536)
//   W3c  [h=2][128][128] swz @139264 (32768)

typedef unsigned short u16;
typedef unsigned int   u32;
typedef __attribute__((ext_vector_type(8))) short short8;
typedef __attribute__((ext_vector_type(4))) float f32x4;

#define MFMA16 __builtin_amdgcn_mfma_f32_16x16x32_bf16

__device__ __forceinline__ float silu_f(float v) { return v / (1.0f + __expf(-v)); }
__device__ __forceinline__ u16 f2bf(float f) {
    u32 u = __float_as_uint(f);
    return (u16)((u + 0x7fff + ((u >> 16) & 1)) >> 16);
}
__device__ __forceinline__ float bf2f(u16 h) { return __uint_as_float(((u32)h) << 16); }
__device__ __forceinline__ u32 pkbf(float a, float b) {
    __hip_bfloat162 h2 = __float22bfloat162_rn(make_float2(a, b));
    u32 r; __builtin_memcpy(&r, &h2, 4); return r;
}
__device__ __forceinline__ int key3(int r) { return (r ^ (r >> 2)) & 7; }

__global__ void prep_weights(const float* __restrict__ W1,
                             const float* __restrict__ We,
                             const float* __restrict__ W3,
                             u16* __restrict__ ws)
{
    int idx = blockIdx.x * 256 + threadIdx.x;
    if (idx < 36864) {                       // W1 hi+lo, K-chunks of 64, stride 72
        int kc = idx / 9216, r = idx % 9216;
        int n = r / 72, j = r % 72;
        float v = (j < 64) ? W1[n * 256 + kc * 64 + j] : 0.0f;
        u16 h = f2bf(v);
        float lo = v - bf2f(h);
        ws[idx] = h;
        ws[36864 + idx] = f2bf(lo);
    } else if (idx < 102400) {               // We center taps, [e][128][128] swz
        int i = idx - 36864;
        int e = i >> 14, r = i & 16383;
        int o = r >> 7, rem = r & 127;
        int ps = rem >> 3, t = rem & 7;
        int gi = (ps & 8) | ((ps ^ key3(o)) & 7);
        int c = gi * 8 + t;
        ws[73728 + i] = f2bf(We[(size_t)(((e * 128 + o) * 128 + c) * 9) + 4]);
    } else if (idx < 135168) {               // W3, [h][128][128] swz
        int i = idx - 102400;
        int h = i >> 14, r = i & 16383;
        int o = r >> 7, rem = r & 127;
        int ps = rem >> 3, t = rem & 7;
        int gi = (ps & 8) | ((ps ^ key3(o)) & 7);
        int c = gi * 8 + t;
        ws[139264 + i] = f2bf(W3[(size_t)(h * 128 + o) * 128 + c]);
    }
}

// Linear DMA of a 32 KB chunk with 512 threads (2048 16B-units, 4/thread).
__device__ __forceinline__ void stage_chunk(const u16* __restrict__ g, u16* l, int tid) {
#pragma unroll
    for (int i = 0; i < 4; ++i)
        __builtin_amdgcn_global_load_lds(g + (size_t)(i * 512 + tid) * 8,
                                         l + (size_t)(i * 512 + (tid & 448)) * 8, 16, 0, 0);
}

// One block = 64 px, 512 threads (8 waves: wm=row-tile 0..3, wn=channel-half).
// GEMM fragment arithmetic bit-identical to R11; router partials exchanged in fp32.
__global__ __launch_bounds__(512, 4)
void fused_moe_mfma(const float* __restrict__ x,
                    const float* __restrict__ b1g,
                    const float* __restrict__ Wrg,
                    const float* __restrict__ brg,
                    const float* __restrict__ beg,
                    const float* __restrict__ b3g,
                    const u16* __restrict__ wbf,
                    float* __restrict__ out)
{
    __shared__ __align__(16) unsigned char smem[81920];
    // P1 (dead after P1):
    u16*   const sWhi = (u16*)(smem);             // [128][72] = 18432 B
    u16*   const sWlo = (u16*)(smem + 18432);
    u16*   const sAhi = (u16*)(smem + 36864);     // [64][72], quad-XOR-swizzled
    u16*   const sAlo = (u16*)(smem + 46080);     // ends 55296
    // P2/P3:
    u16*   const A2   = (u16*)(smem);             // [64][128] swz = 16384 B (A2/A3)
    u16*   const bufA = (u16*)(smem + 16384);     // 32768 B
    u16*   const bufB = (u16*)(smem + 49152);     // 32768 B
    float* const sLg  = (float*)(smem + 49152);   // [2][64][4] f32 (bufB head; barrier-protected)
    float* const sY   = (float*)(smem + 16384);   // [128][64] f32 swz (bufA region)

    const int tid = threadIdx.x;
    const int l  = tid & 63;
    const int w  = tid >> 6;        // 0..7
    const int wm = w & 3, wn = w >> 2;
    const int lr = l & 15;
    const int g  = l >> 4;
    const int mrow = 16 * wm + 4 * g;
    const int arow = 16 * wm + lr;
    const int ak3 = key3(arow);
    int oc[4], ok3[4];
#pragma unroll
    for (int f = 0; f < 4; ++f) { oc[f] = 64 * wn + 16 * f + lr; ok3[f] = key3(oc[f]); }

    const int n0  = blockIdx.x << 6;
    const float* xb = x   + ((size_t)(n0 >> 12) * 256) * 4096 + (n0 & 4095);
    float*       ob = out + ((size_t)(n0 >> 12) * 256) * 4096 + (n0 & 4095);

    // ============ P1: GEMM1, split-bf16 4-pass (bit-identical to R11) ============
    f32x4 acc1[4];
#pragma unroll
    for (int f = 0; f < 4; ++f) acc1[f] = (f32x4){0.f, 0.f, 0.f, 0.f};

    const int c2 = tid >> 4;        // channel-pair 0..31
    const int m4 = (tid & 15) << 2; // pixel row base

#pragma unroll 1
    for (int kc = 0; kc < 4; ++kc) {
        __syncthreads();
        const float* xa = xb + (size_t)(kc * 64 + 2 * c2) * 4096 + m4;
        float4 fa = *(const float4*)xa;
        float4 fb = *(const float4*)(xa + 4096);
        // DMA W1 chunk kc (hi+lo, 1152 16B-units each)
#pragma unroll
        for (int i = 0; i < 3; ++i) {
            int idx = i * 512 + tid;
            if (idx < 1152) {
                int ub = i * 512 + (tid & 448);
                __builtin_amdgcn_global_load_lds(wbf + (size_t)kc * 9216 + (size_t)idx * 8,
                                                 sWhi + (size_t)ub * 8, 16, 0, 0);
                __builtin_amdgcn_global_load_lds(wbf + (size_t)(36864 + kc * 9216) + (size_t)idx * 8,
                                                 sWlo + (size_t)ub * 8, 16, 0, 0);
            }
        }
        // split conversion -> A hi/lo, quad-XOR-swizzled store (fixes 32-way conflict)
        {
            u32* H = (u32*)sAhi; u32* L = (u32*)sAlo;
            float fav[4] = {fa.x, fa.y, fa.z, fa.w};
            float fbv[4] = {fb.x, fb.y, fb.z, fb.w};
#pragma unroll
            for (int r = 0; r < 4; ++r) {
                int row = m4 + r;
                u32 hi = pkbf(fav[r], fbv[r]);
                float la = fav[r] - __uint_as_float(hi << 16);
                float lb = fbv[r] - __uint_as_float(hi & 0xffff0000u);
                int jj = c2 ^ (key3(row) << 2);
                H[row * 36 + jj] = hi; L[row * 36 + jj] = pkbf(la, lb);
            }
        }
        __syncthreads();             // drains DMA + LDS writes
#pragma unroll
        for (int ks = 0; ks < 2; ++ks) {
            int jb = (ks * 16 + g * 4) ^ (ak3 << 2);   // swizzled u32 quad base
            short8 ah = *(const short8*)&sAhi[arow * 72 + jb * 2];
            short8 al = *(const short8*)&sAlo[arow * 72 + jb * 2];
#pragma unroll
            for (int f = 0; f < 4; ++f) {
                int bo = oc[f] * 72 + ks * 32 + g * 8;
                short8 bh = *(const short8*)&sWhi[bo];
                short8 bl = *(const short8*)&sWlo[bo];
                acc1[f] = MFMA16(ah, bh, acc1[f], 0, 0, 0);
                acc1[f] = MFMA16(al, bh, acc1[f], 0, 0, 0);
                acc1[f] = MFMA16(ah, bl, acc1[f], 0, 0, 0);
                acc1[f] = MFMA16(al, bl, acc1[f], 0, 0, 0);
            }
        }
    }
    __syncthreads();                 // P1 readers done; bufA region free
    stage_chunk(wbf + 73728, bufA, tid);   // expert 0 flies under the epilogue

    // ============ epilogue: xin fp32; A2 swz; router partials via sLg ============
    float xin[4][4];
#pragma unroll
    for (int f = 0; f < 4; ++f) {
        float bias = b1g[oc[f]];
#pragma unroll
        for (int i = 0; i < 4; ++i) xin[f][i] = silu_f(acc1[f][i] + bias);
    }
#pragma unroll
    for (int f = 0; f < 4; ++f) {
        int c = oc[f], cg = c >> 3;
#pragma unroll
        for (int i = 0; i < 4; ++i) {
            int m = mrow + i;
            int ps = (cg & 8) | ((cg ^ key3(m)) & 7);
            A2[m * 128 + ps * 8 + (c & 7)] = f2bf(xin[f][i]);
        }
    }
    float lg[4][4];
#pragma unroll
    for (int e = 0; e < 4; ++e)
#pragma unroll
        for (int i = 0; i < 4; ++i) lg[e][i] = 0.f;
#pragma unroll
    for (int f = 0; f < 4; ++f) {
        int c = oc[f];
        float w0 = Wrg[c], w1 = Wrg[128 + c], w2 = Wrg[256 + c], w3 = Wrg[384 + c];
#pragma unroll
        for (int i = 0; i < 4; ++i) {
            float xv = xin[f][i];
            lg[0][i] += xv * w0; lg[1][i] += xv * w1;
            lg[2][i] += xv * w2; lg[3][i] += xv * w3;
        }
    }
#pragma unroll
    for (int d = 1; d < 16; d <<= 1)
#pragma unroll
        for (int e = 0; e < 4; ++e)
#pragma unroll
            for (int i = 0; i < 4; ++i)
                lg[e][i] += __shfl_xor(lg[e][i], d, 64);
    if (lr == 0) {
#pragma unroll
        for (int i = 0; i < 4; ++i)
#pragma unroll
            for (int e = 0; e < 4; ++e)
                sLg[(wn * 64 + mrow + i) * 4 + e] = lg[e][i];
    }
    __syncthreads();                 // sLg visible; e0 DMA drained

    float br0 = brg[0], br1 = brg[1], br2 = brg[2], br3 = brg[3];
    float rw[4][4];
#pragma unroll
    for (int i = 0; i < 4; ++i) {
        int m = mrow + i;
        float le0 = sLg[m * 4 + 0] + sLg[(64 + m) * 4 + 0] + br0;
        float le1 = sLg[m * 4 + 1] + sLg[(64 + m) * 4 + 1] + br1;
        float le2 = sLg[m * 4 + 2] + sLg[(64 + m) * 4 + 2] + br2;
        float le3 = sLg[m * 4 + 3] + sLg[(64 + m) * 4 + 3] + br3;
        int c0 = (le1 > le0) + (le2 > le0) + (le3 > le0);
        int c1 = (le0 >= le1) + (le2 > le1) + (le3 > le1);
        int c2r = (le0 >= le2) + (le1 >= le2) + (le3 > le2);
        int c3 = (le0 >= le3) + (le1 >= le3) + (le2 >= le3);
        float m0 = fmaxf(fmaxf(le0, le1), fmaxf(le2, le3));
        float p0 = (c0 < 2) ? __expf(le0 - m0) : 0.f;
        float p1 = (c1 < 2) ? __expf(le1 - m0) : 0.f;
        float p2 = (c2r < 2) ? __expf(le2 - m0) : 0.f;
        float p3 = (c3 < 2) ? __expf(le3 - m0) : 0.f;
        float inv = 1.0f / (p0 + p1 + p2 + p3);
        rw[0][i] = p0 * inv; rw[1][i] = p1 * inv;
        rw[2][i] = p2 * inv; rw[3][i] = p3 * inv;
    }
    __syncthreads();                 // ALL sLg reads done -> bufB may receive DMA
    stage_chunk(wbf + 73728 + 16384, bufB, tid);   // expert 1

    // ============ P2: experts (chain: chunk e+2 staged as buffer frees) ============
    f32x4 macc[4];
#pragma unroll
    for (int f = 0; f < 4; ++f) macc[f] = (f32x4){0.f, 0.f, 0.f, 0.f};

#pragma unroll 1
    for (int e = 0; e < 4; ++e) {
        const u16* Wb = (e & 1) ? bufB : bufA;
        f32x4 acce[4];
#pragma unroll
        for (int f = 0; f < 4; ++f) acce[f] = (f32x4){0.f, 0.f, 0.f, 0.f};
#pragma unroll
        for (int ks = 0; ks < 4; ++ks) {
            int gi = ks * 4 + g;
            int psA = (gi & 8) | ((gi ^ ak3) & 7);
            short8 a = *(const short8*)&A2[arow * 128 + psA * 8];
#pragma unroll
            for (int f = 0; f < 4; ++f) {
                int psB = (gi & 8) | ((gi ^ ok3[f]) & 7);
                short8 bb = *(const short8*)&Wb[oc[f] * 128 + psB * 8];
                acce[f] = MFMA16(a, bb, acce[f], 0, 0, 0);
            }
        }
#pragma unroll
        for (int f = 0; f < 4; ++f) {
            float bias = beg[e * 128 + oc[f]];
#pragma unroll
            for (int i = 0; i < 4; ++i)
                macc[f][i] += rw[e][i] * silu_f(acce[f][i] + bias);
        }
        __syncthreads();             // Wb readers done; drains chunk e+1
        if (e < 2)       stage_chunk(wbf + 73728 + (e + 2) * 16384, (e & 1) ? bufB : bufA, tid);
        else if (e == 2) stage_chunk(wbf + 139264, bufA, tid);   // W3 h0
    }

    // moe -> A3 (A2 region; all A2 readers passed the e=3 barrier)
#pragma unroll
    for (int f = 0; f < 4; ++f) {
        int c = oc[f], cg = c >> 3;
#pragma unroll
        for (int i = 0; i < 4; ++i) {
            int m = mrow + i;
            int ps = (cg & 8) | ((cg ^ key3(m)) & 7);
            A2[m * 128 + ps * 8 + (c & 7)] = f2bf(macc[f][i]);
        }
    }
    __syncthreads();                 // A3 visible; drains W3 h0
    stage_chunk(wbf + 139264 + 16384, bufB, tid);   // W3 h1

    // ============ P3: GEMM3 + residual ============
#pragma unroll 1
    for (int h = 0; h < 2; ++h) {
        const u16* Wb = h ? bufB : bufA;
        f32x4 acc3[4];
#pragma unroll
        for (int f = 0; f < 4; ++f) acc3[f] = (f32x4){0.f, 0.f, 0.f, 0.f};
#pragma unroll
        for (int ks = 0; ks < 4; ++ks) {
            int gi = ks * 4 + g;
            int psA = (gi & 8) | ((gi ^ ak3) & 7);
            short8 a = *(const short8*)&A2[arow * 128 + psA * 8];
#pragma unroll
            for (int f = 0; f < 4; ++f) {
                int psB = (gi & 8) | ((gi ^ ok3[f]) & 7);
                short8 bb = *(const short8*)&Wb[oc[f] * 128 + psB * 8];
                acc3[f] = MFMA16(a, bb, acc3[f], 0, 0, 0);
            }
        }
        __syncthreads();             // h=0: frees bufA (sY overlays), drains W3 h1
        int mg = mrow >> 2;          // 4*wm + g, 0..15
#pragma unroll
        for (int f = 0; f < 4; ++f) {
            int o = oc[f];
            float bias = b3g[h * 128 + o];
            float4 v;
            v.x = silu_f(acc3[f][0] + bias);
            v.y = silu_f(acc3[f][1] + bias);
            v.z = silu_f(acc3[f][2] + bias);
            v.w = silu_f(acc3[f][3] + bias);
            *(float4*)&sY[o * 64 + ((mg ^ ok3[f]) << 2)] = v;
        }
        __syncthreads();
#pragma unroll
        for (int q = 0; q < 4; ++q) {    // coalesced residual-add + store
            int idx = q * 512 + tid;
            int o = idx >> 4, mq = idx & 15;
            int og = h * 128 + o;
            float4 vy = *(const float4*)&sY[o * 64 + ((mq ^ key3(o)) << 2)];
            size_t goff = (size_t)og * 4096 + (mq << 2);
            float4 r = *(const float4*)&xb[goff];
            vy.x += r.x; vy.y += r.y; vy.z += r.z; vy.w += r.w;
            *(float4*)&ob[goff] = vy;
        }
        if (h == 0) __syncthreads(); // sY readers done before h=1 overwrites
    }
}

extern "C" void kernel_launch(void* const* d_in, const int* in_sizes, int n_in,
                              void* d_out, int out_size, void* d_ws, size_t ws_size,
                              hipStream_t stream)
{
    const float* x  = (const float*)d_in[0];
    const float* W1 = (const float*)d_in[1];
    const float* b1 = (const float*)d_in[2];
    const float* Wr = (const float*)d_in[3];
    const float* br = (const float*)d_in[4];
    const float* We = (const float*)d_in[5];
    const float* be = (const float*)d_in[6];
    const float* W3 = (const float*)d_in[7];
    const float* b3 = (const float*)d_in[8];
    float* outp = (float*)d_out;
    u16* wbf = (u16*)d_ws;

    hipLaunchKernelGGL(prep_weights, dim3(528), dim3(256), 0, stream,
                       W1, We, W3, wbf);
    hipLaunchKernelGGL(fused_moe_mfma, dim3(512), dim3(512), 0, stream,
                       x, b1, Wr, br, be, b3, wbf, outp);
}